// Round 4
// baseline (106.607 us; speedup 1.0000x reference)
//
#include <hip/hip_runtime.h>

// MultiStep n-step return bookkeeping. B=2048, T=512, D=64, N=3, GAMMA=0.99.
// Inputs: done(int32 bool), mask(int32 bool), reward(f32), next_obs(f32).
// Outputs (all f32, concat): gamma_masked[B,T,1], steps[B,T,1], nonterminal[B,T,1],
// partial_return[B,T,1], next_obs_out[B,T,D], done_out[B,T,1].
//
// Single fused kernel, one block per row, ONE __syncthreads:
//  - stage done/mask/reward in LDS (vectorized int4/float4)
//  - per-wave ballot bookkeeping (no atomics)
//  - row->wave assignment INTERLEAVED (wave w, iter i -> rows i*16+w*4+{0..3})
//    so each wave gets an equal share of masked (load-bearing) rows; mask is a
//    prefix, so contiguous 128-row ownership left waves 0-1 with all the loads.
//  - nontemporal loads (read-once) + nontemporal stores (write-once).

constexpr int   NSTEP = 3;
constexpr int   Bb    = 2048;
constexpr int   Tt    = 512;
constexpr int   Dd    = 64;
constexpr float GAM   = 0.99f;
constexpr long long BT = (long long)Bb * Tt;

typedef float f4v __attribute__((ext_vector_type(4)));

__global__ __launch_bounds__(256) void multistep_fused(
    const int* __restrict__ done, const int* __restrict__ mask,
    const float* __restrict__ reward, const float* __restrict__ next_obs,
    float* __restrict__ out)
{
    const int b    = blockIdx.x;
    const int tid  = threadIdx.x;
    const int lane = tid & 63;
    const int wid  = tid >> 6;

    __shared__ unsigned char done_s[Tt];
    __shared__ unsigned char mask_s[Tt];
    __shared__ float g_s[Tt + NSTEP];
    __shared__ float r_s[Tt + NSTEP];

    const int4*   d4 = (const int4*)(done + (long long)b * Tt);
    const int4*   m4 = (const int4*)(mask + (long long)b * Tt);
    const float4* r4 = (const float4*)(reward + (long long)b * Tt);
    const float*  orow = next_obs + (long long)b * Tt * Dd;

    if (tid < Tt / 4) {
        int4   dv = d4[tid];
        float4 rv = r4[tid];
        int base = 4 * tid;
        done_s[base]     = dv.x != 0; done_s[base + 1] = dv.y != 0;
        done_s[base + 2] = dv.z != 0; done_s[base + 3] = dv.w != 0;
        r_s[base] = rv.x; r_s[base + 1] = rv.y;
        r_s[base + 2] = rv.z; r_s[base + 3] = rv.w;
    } else {
        int tt = tid - Tt / 4;
        int4 mv = m4[tt];
        int base = 4 * tt;
        mask_s[base]     = mv.x != 0; mask_s[base + 1] = mv.y != 0;
        mask_s[base + 2] = mv.z != 0; mask_s[base + 3] = mv.w != 0;
        g_s[base]     = mv.x ? GAM : 1.0f; g_s[base + 1] = mv.y ? GAM : 1.0f;
        g_s[base + 2] = mv.z ? GAM : 1.0f; g_s[base + 3] = mv.w ? GAM : 1.0f;
    }
    if (tid < NSTEP) { g_s[Tt + tid] = 1.0f; r_s[Tt + tid] = 0.0f; }
    __syncthreads();

    // ---- per-wave bookkeeping: ballots over done bits (no atomics, no syncs) ----
    int total = 0;
    int p = Tt;
    unsigned long long bits[Tt / 64];
#pragma unroll
    for (int g = 0; g < Tt / 64; ++g) {
        int v = done_s[g * 64 + lane];
        unsigned long long bm = __ballot(v != 0);
        bits[g] = bm;
        total += __popcll(bm);
        if (p == Tt && bm) p = g * 64 + __builtin_ctzll(bm);
    }
    // forced terminal at T-1 when total != 1 and it's not already done
    if (total != 1 && !done_s[Tt - 1]) {
        bits[Tt / 64 - 1] |= 0x8000000000000000ull;
        if (p == Tt) p = Tt - 1;
    }
    const float last_done = (float)total;  // sum(terminal*done) == sum(done)

    // gather last_obs[d] for d = lane (uniform bit loop, coalesced 256B loads)
    float acc = 0.0f;
#pragma unroll
    for (int g = 0; g < Tt / 64; ++g) {
        unsigned long long bm = bits[g];
        while (bm) {
            int t = g * 64 + __builtin_ctzll(bm);
            bm &= bm - 1;
            acc += orow[(long long)t * Dd + lane];
        }
    }

    float* out_gm  = out;
    float* out_st  = out + BT;
    float* out_nt  = out + 2 * BT;
    float* out_pr  = out + 3 * BT;
    float* out_obs = out + 4 * BT;
    float* out_do  = out + 4 * BT + (long long)Dd * BT;
    const long long rowoff = (long long)b * Tt;

    // ---- scalar-per-t outputs: wave w owns rows [w*128, w*128+128) ----
    const int tbase = wid * 128;
#pragma unroll
    for (int k = 0; k < 2; ++k) {
        int t = tbase + k * 64 + lane;
        float gm = g_s[t] * g_s[t + 1] * g_s[t + 2] * g_s[t + 3];
        int steps = p - t + 1;
        steps = steps < 0 ? 0 : (steps > NSTEP + 1 ? NSTEP + 1 : steps);
        float nonterm = (t <= p) ? 1.0f : 0.0f;
        float pr = r_s[t] + 0.99f * r_s[t + 1] + 0.9801f * r_s[t + 2]
                 + 0.970299f * r_s[t + 3];
        float dval = ((t + NSTEP < Tt) ? (float)done_s[t + NSTEP] : 0.0f)
                   + ((t + NSTEP > p) ? last_done : 0.0f);
        out_gm[rowoff + t] = gm;
        out_st[rowoff + t] = (float)steps;
        out_nt[rowoff + t] = nonterm;
        out_pr[rowoff + t] = pr;
        out_do[rowoff + t] = (mask_s[t] && dval > 0.5f) ? 1.0f : 0.0f;
    }

    // ---- next_obs streaming: interleaved row->wave map for load balance ----
    const int dlane = (lane & 15) * 4;  // 16 lanes x float4 cover D=64
    const int trow  = lane >> 4;        // 4 rows per wave-iteration
    f4v l4;
    l4.x = __shfl(acc, dlane, 64);
    l4.y = __shfl(acc, dlane + 1, 64);
    l4.z = __shfl(acc, dlane + 2, 64);
    l4.w = __shfl(acc, dlane + 3, 64);

    float* orow_out = out_obs + rowoff * Dd;
#pragma unroll 8
    for (int i = 0; i < Tt / 16; ++i) {
        int t = i * 16 + wid * 4 + trow;   // interleaved: equal masked share/wave
        int s = t + NSTEP;
        f4v v = {0.0f, 0.0f, 0.0f, 0.0f};
        if (mask_s[t]) {
            if (s < Tt)
                v = __builtin_nontemporal_load(
                        (const f4v*)(orow + (long long)s * Dd + dlane));
            if (s > p) v += l4;
        }
        __builtin_nontemporal_store(v, (f4v*)(orow_out + (long long)t * Dd + dlane));
    }
}

extern "C" void kernel_launch(void* const* d_in, const int* in_sizes, int n_in,
                              void* d_out, int out_size, void* d_ws, size_t ws_size,
                              hipStream_t stream) {
    const int*   done     = (const int*)d_in[0];
    const int*   mask     = (const int*)d_in[1];
    const float* reward   = (const float*)d_in[2];
    const float* next_obs = (const float*)d_in[3];
    float*       out      = (float*)d_out;

    multistep_fused<<<Bb, 256, 0, stream>>>(done, mask, reward, next_obs, out);
}

// Round 5
// 91.467 us; speedup vs baseline: 1.1655x; 1.1655x over previous
//
#include <hip/hip_runtime.h>

// MultiStep n-step return bookkeeping. B=2048, T=512, D=64, N=3, GAMMA=0.99.
// Inputs: done(int32 bool), mask(int32 bool), reward(f32), next_obs(f32).
// Outputs (all f32, concat): gamma_masked[B,T,1], steps[B,T,1], nonterminal[B,T,1],
// partial_return[B,T,1], next_obs_out[B,T,D], done_out[B,T,1].
//
// R3 structure (best: 84.2 us, ~5.98 TB/s effective on 503 MB compulsory traffic):
//  - one block per row, ONE __syncthreads
//  - stage done/mask/reward in LDS (vectorized int4/float4)
//  - per-wave ballot bookkeeping (no atomics, no extra syncs)
//  - wave w owns contiguous rows [w*128, w*128+128): keeps each wave's
//    load/store stream contiguous (32 KB range). R4's interleaved map +
//    NT loads regressed 27% — DRAM locality beats per-wave load balance.
//  - nontemporal STORES only (output never re-read); plain loads.

constexpr int   NSTEP = 3;
constexpr int   Bb    = 2048;
constexpr int   Tt    = 512;
constexpr int   Dd    = 64;
constexpr float GAM   = 0.99f;
constexpr long long BT = (long long)Bb * Tt;

typedef float f4v __attribute__((ext_vector_type(4)));

__global__ __launch_bounds__(256) void multistep_fused(
    const int* __restrict__ done, const int* __restrict__ mask,
    const float* __restrict__ reward, const float* __restrict__ next_obs,
    float* __restrict__ out)
{
    const int b    = blockIdx.x;
    const int tid  = threadIdx.x;
    const int lane = tid & 63;
    const int wid  = tid >> 6;

    __shared__ unsigned char done_s[Tt];
    __shared__ unsigned char mask_s[Tt];
    __shared__ float g_s[Tt + NSTEP];
    __shared__ float r_s[Tt + NSTEP];

    const int4*   d4 = (const int4*)(done + (long long)b * Tt);
    const int4*   m4 = (const int4*)(mask + (long long)b * Tt);
    const float4* r4 = (const float4*)(reward + (long long)b * Tt);
    const float*  orow = next_obs + (long long)b * Tt * Dd;

    if (tid < Tt / 4) {
        int4   dv = d4[tid];
        float4 rv = r4[tid];
        int base = 4 * tid;
        done_s[base]     = dv.x != 0; done_s[base + 1] = dv.y != 0;
        done_s[base + 2] = dv.z != 0; done_s[base + 3] = dv.w != 0;
        r_s[base] = rv.x; r_s[base + 1] = rv.y;
        r_s[base + 2] = rv.z; r_s[base + 3] = rv.w;
    } else {
        int tt = tid - Tt / 4;
        int4 mv = m4[tt];
        int base = 4 * tt;
        mask_s[base]     = mv.x != 0; mask_s[base + 1] = mv.y != 0;
        mask_s[base + 2] = mv.z != 0; mask_s[base + 3] = mv.w != 0;
        g_s[base]     = mv.x ? GAM : 1.0f; g_s[base + 1] = mv.y ? GAM : 1.0f;
        g_s[base + 2] = mv.z ? GAM : 1.0f; g_s[base + 3] = mv.w ? GAM : 1.0f;
    }
    if (tid < NSTEP) { g_s[Tt + tid] = 1.0f; r_s[Tt + tid] = 0.0f; }
    __syncthreads();

    // ---- per-wave bookkeeping: ballots over done bits (no atomics, no syncs) ----
    int total = 0;
    int p = Tt;
    unsigned long long bits[Tt / 64];
#pragma unroll
    for (int g = 0; g < Tt / 64; ++g) {
        int v = done_s[g * 64 + lane];
        unsigned long long bm = __ballot(v != 0);
        bits[g] = bm;
        total += __popcll(bm);
        if (p == Tt && bm) p = g * 64 + __builtin_ctzll(bm);
    }
    // forced terminal at T-1 when total != 1 and it's not already done
    if (total != 1 && !done_s[Tt - 1]) {
        bits[Tt / 64 - 1] |= 0x8000000000000000ull;
        if (p == Tt) p = Tt - 1;
    }
    const float last_done = (float)total;  // sum(terminal*done) == sum(done)

    // gather last_obs[d] for d = lane (uniform bit loop, coalesced 256B loads)
    float acc = 0.0f;
#pragma unroll
    for (int g = 0; g < Tt / 64; ++g) {
        unsigned long long bm = bits[g];
        while (bm) {
            int t = g * 64 + __builtin_ctzll(bm);
            bm &= bm - 1;
            acc += orow[(long long)t * Dd + lane];
        }
    }

    float* out_gm  = out;
    float* out_st  = out + BT;
    float* out_nt  = out + 2 * BT;
    float* out_pr  = out + 3 * BT;
    float* out_obs = out + 4 * BT;
    float* out_do  = out + 4 * BT + (long long)Dd * BT;
    const long long rowoff = (long long)b * Tt;

    // ---- scalar-per-t outputs: wave w owns rows [w*128, w*128+128) ----
    const int tbase = wid * 128;
#pragma unroll
    for (int k = 0; k < 2; ++k) {
        int t = tbase + k * 64 + lane;
        float gm = g_s[t] * g_s[t + 1] * g_s[t + 2] * g_s[t + 3];
        int steps = p - t + 1;
        steps = steps < 0 ? 0 : (steps > NSTEP + 1 ? NSTEP + 1 : steps);
        float nonterm = (t <= p) ? 1.0f : 0.0f;
        float pr = r_s[t] + 0.99f * r_s[t + 1] + 0.9801f * r_s[t + 2]
                 + 0.970299f * r_s[t + 3];
        float dval = ((t + NSTEP < Tt) ? (float)done_s[t + NSTEP] : 0.0f)
                   + ((t + NSTEP > p) ? last_done : 0.0f);
        out_gm[rowoff + t] = gm;
        out_st[rowoff + t] = (float)steps;
        out_nt[rowoff + t] = nonterm;
        out_pr[rowoff + t] = pr;
        out_do[rowoff + t] = (mask_s[t] && dval > 0.5f) ? 1.0f : 0.0f;
    }

    // ---- next_obs streaming: wave w owns rows [w*128, w*128+128) ----
    const int dlane = (lane & 15) * 4;  // 16 lanes x float4 cover D=64
    const int trow  = lane >> 4;        // 4 rows per wave-iteration
    f4v l4;
    l4.x = __shfl(acc, dlane, 64);
    l4.y = __shfl(acc, dlane + 1, 64);
    l4.z = __shfl(acc, dlane + 2, 64);
    l4.w = __shfl(acc, dlane + 3, 64);

    float* orow_out = out_obs + rowoff * Dd;
#pragma unroll 4
    for (int t0 = 0; t0 < 128; t0 += 4) {
        int t = tbase + t0 + trow;
        int s = t + NSTEP;
        f4v v = {0.0f, 0.0f, 0.0f, 0.0f};
        if (mask_s[t]) {
            if (s < Tt) v = *(const f4v*)(orow + (long long)s * Dd + dlane);
            if (s > p) v += l4;
        }
        __builtin_nontemporal_store(v, (f4v*)(orow_out + (long long)t * Dd + dlane));
    }
}

extern "C" void kernel_launch(void* const* d_in, const int* in_sizes, int n_in,
                              void* d_out, int out_size, void* d_ws, size_t ws_size,
                              hipStream_t stream) {
    const int*   done     = (const int*)d_in[0];
    const int*   mask     = (const int*)d_in[1];
    const float* reward   = (const float*)d_in[2];
    const float* next_obs = (const float*)d_in[3];
    float*       out      = (float*)d_out;

    multistep_fused<<<Bb, 256, 0, stream>>>(done, mask, reward, next_obs, out);
}